// Round 8
// baseline (129220.349 us; speedup 1.0000x reference)
//
#include <hip/hip_runtime.h>
#include <math.h>

#define N 2048
#define DIMS 784
#define BIGV 1.0e6f
#define NC 784

// two-sided block Jacobi config: 128 teams of width 16, 32x32 local tiles
#define NB 128
#define NPAIRS 64
#define NSWEEPS 18
#define NTRI 2016      // 64*63/2 upper-tri pair tiles
#define NVS  2048      // 64 pairs * 32 V row-stripes

// round-robin pairing over nteams: round r in [0,nteams-1), pair m in [0,nteams/2)
__device__ __forceinline__ void rr_pairN(int r, int m, int nteams, int& bi, int& bj) {
    int n1 = nteams - 1;
    if (m == 0) { bi = n1; bj = r % n1; }
    else { bi = (r + m) % n1; bj = (r - m + n1) % n1; }
}

// ---------------- distances ----------------
__global__ void k_rowsq(const float* __restrict__ X, float* __restrict__ sq) {
    int wave = threadIdx.x >> 6, lane = threadIdx.x & 63;
    int row = blockIdx.x * 4 + wave;
    const float* xr = X + (size_t)row * DIMS;
    float s = 0.f;
    for (int k = lane; k < DIMS; k += 64) { float v = xr[k]; s += v * v; }
    for (int off = 32; off; off >>= 1) s += __shfl_down(s, off);
    if (lane == 0) sq[row] = s;
}

__global__ void __launch_bounds__(256) k_dist(const float* __restrict__ X,
                                              const float* __restrict__ sq,
                                              float* __restrict__ out) {
    __shared__ float As[64][17], Bs[64][17];
    int ti = blockIdx.y, tj = blockIdx.x, t = threadIdx.x;
    int tx = t & 15, ty = t >> 4;
    float acc[4][4] = {};
    for (int k0 = 0; k0 < DIMS; k0 += 16) {
        for (int e = 0; e < 4; e++) {
            int idx = t + e * 256; int r = idx >> 4, c = idx & 15;
            As[r][c] = X[(size_t)(ti * 64 + r) * DIMS + k0 + c];
            Bs[r][c] = X[(size_t)(tj * 64 + r) * DIMS + k0 + c];
        }
        __syncthreads();
        for (int k = 0; k < 16; k++) {
            float a[4], b[4];
            for (int e = 0; e < 4; e++) a[e] = As[ty * 4 + e][k];
            for (int f = 0; f < 4; f++) b[f] = Bs[tx * 4 + f][k];
            for (int e = 0; e < 4; e++)
                for (int f = 0; f < 4; f++) acc[e][f] += a[e] * b[f];
        }
        __syncthreads();
    }
    for (int e = 0; e < 4; e++)
        for (int f = 0; f < 4; f++) {
            int gi = ti * 64 + ty * 4 + e, gj = tj * 64 + tx * 4 + f;
            float d2 = sq[gi] + sq[gj] - 2.f * acc[e][f];
            out[(size_t)gi * N + gj] = sqrtf(fmaxf(d2, 0.f));
        }
}

// ---------------- KNN graph ----------------
__global__ void k_knn(const float* __restrict__ dist, float* __restrict__ G) {
    int i = blockIdx.x, t = threadIdx.x;
    float bv[6]; int bidx[6];
    for (int k = 0; k < 6; k++) { bv[k] = 3.4e38f; bidx[k] = N; }
    const float* dr = dist + (size_t)i * N;
    for (int j = t; j < N; j += 256) {
        float v = dr[j];
        bool ins = (v < bv[5]) || (v == bv[5] && j < bidx[5]);
        if (ins) {
            int k = 5;
            while (k > 0) {
                bool mv = (v < bv[k - 1]) || (v == bv[k - 1] && j < bidx[k - 1]);
                if (!mv) break;
                bv[k] = bv[k - 1]; bidx[k] = bidx[k - 1]; k--;
            }
            bv[k] = v; bidx[k] = j;
        }
    }
    __shared__ float lv[256][6]; __shared__ int li[256][6];
    for (int k = 0; k < 6; k++) { lv[t][k] = bv[k]; li[t][k] = bidx[k]; }
    __syncthreads();
    for (int off = 128; off >= 1; off >>= 1) {
        if (t < off) {
            float av[6], cv[6]; int ai[6], ci[6];
            for (int k = 0; k < 6; k++) { av[k] = lv[t][k]; ai[k] = li[t][k]; cv[k] = lv[t + off][k]; ci[k] = li[t + off][k]; }
            float mv[6]; int mi[6]; int pa = 0, pb = 0;
            for (int k = 0; k < 6; k++) {
                bool ta;
                if (pa >= 6) ta = false;
                else if (pb >= 6) ta = true;
                else ta = (av[pa] < cv[pb]) || (av[pa] == cv[pb] && ai[pa] < ci[pb]);
                if (ta) { mv[k] = av[pa]; mi[k] = ai[pa]; pa++; }
                else    { mv[k] = cv[pb]; mi[k] = ci[pb]; pb++; }
            }
            for (int k = 0; k < 6; k++) { lv[t][k] = mv[k]; li[t][k] = mi[k]; }
        }
        __syncthreads();
    }
    float sv[6]; int si[6];
    for (int k = 0; k < 6; k++) { sv[k] = lv[0][k]; si[k] = li[0][k]; }
    for (int j = t; j < N; j += 256) {
        float val = BIGV;
        for (int k = 0; k < 6; k++) if (j == si[k]) val = sv[k];
        G[(size_t)i * N + j] = val;
    }
}

__global__ void k_symdiag(float* __restrict__ G) {
    int idx = blockIdx.x * 256 + threadIdx.x;
    int i = idx >> 11, j = idx & 2047;
    if (i == j) { G[idx] = 0.f; return; }
    if (j > i) {
        float a = G[(size_t)i * N + j], b = G[(size_t)j * N + i];
        float m = fminf(a, b);
        G[(size_t)i * N + j] = m; G[(size_t)j * N + i] = m;
    }
}

// ---------------- blocked Floyd-Warshall ----------------
__global__ void __launch_bounds__(256) k_fw12(float* __restrict__ D, int kb) {
    __shared__ float KK[64][65], C[64][65];
    int bx = blockIdx.x, t = threadIdx.x;
    for (int e = 0; e < 16; e++) { int idx = t + e * 256; int r = idx >> 6, c = idx & 63;
        KK[r][c] = D[(size_t)(kb * 64 + r) * N + kb * 64 + c]; }
    __syncthreads();
    int r0 = t >> 2, c0 = (t & 3) * 16;
    for (int k = 0; k < 64; k++) {
        float dk = KK[r0][k];
        for (int c = 0; c < 16; c++) KK[r0][c0 + c] = fminf(KK[r0][c0 + c], dk + KK[k][c0 + c]);
        __syncthreads();
    }
    if (bx == 62) {
        for (int e = 0; e < 16; e++) { int idx = t + e * 256; int r = idx >> 6, c = idx & 63;
            D[(size_t)(kb * 64 + r) * N + kb * 64 + c] = KK[r][c]; }
        return;
    }
    bool rowstripe = bx < 31;
    int o = rowstripe ? bx : bx - 31;
    o += (o >= kb) ? 1 : 0;
    int baseR = rowstripe ? kb : o;
    int baseC = rowstripe ? o : kb;
    for (int e = 0; e < 16; e++) { int idx = t + e * 256; int r = idx >> 6, c = idx & 63;
        C[r][c] = D[(size_t)(baseR * 64 + r) * N + baseC * 64 + c]; }
    __syncthreads();
    if (rowstripe) {
        for (int k = 0; k < 64; k++) {
            float dk = KK[r0][k];
            for (int c = 0; c < 16; c++) C[r0][c0 + c] = fminf(C[r0][c0 + c], dk + C[k][c0 + c]);
            __syncthreads();
        }
    } else {
        for (int k = 0; k < 64; k++) {
            float dk = C[r0][k];
            for (int c = 0; c < 16; c++) C[r0][c0 + c] = fminf(C[r0][c0 + c], dk + KK[k][c0 + c]);
            __syncthreads();
        }
    }
    for (int e = 0; e < 16; e++) { int idx = t + e * 256; int r = idx >> 6, c = idx & 63;
        D[(size_t)(baseR * 64 + r) * N + baseC * 64 + c] = C[r][c]; }
}

__global__ void __launch_bounds__(256) k_fw3(float* __restrict__ D, int kb) {
    int bi = blockIdx.y, bj = blockIdx.x;
    if (bi == kb || bj == kb) return;
    __shared__ float R[64][65], Cl[64][65];
    int t = threadIdx.x;
    for (int e = 0; e < 16; e++) { int idx = t + e * 256; int r = idx >> 6, c = idx & 63;
        R[r][c]  = D[(size_t)(bi * 64 + r) * N + kb * 64 + c];
        Cl[r][c] = D[(size_t)(kb * 64 + r) * N + bj * 64 + c]; }
    __syncthreads();
    int r0 = (t >> 4) * 4, c0 = (t & 15) * 4;
    float acc[4][4];
    for (int e = 0; e < 4; e++) for (int f = 0; f < 4; f++) acc[e][f] = 3.4e38f;
    for (int k = 0; k < 64; k++) {
        float a[4], b[4];
        for (int e = 0; e < 4; e++) a[e] = R[r0 + e][k];
        for (int f = 0; f < 4; f++) b[f] = Cl[k][c0 + f];
        for (int e = 0; e < 4; e++)
            for (int f = 0; f < 4; f++) acc[e][f] = fminf(acc[e][f], a[e] + b[f]);
    }
    for (int e = 0; e < 4; e++)
        for (int f = 0; f < 4; f++) {
            size_t off = (size_t)(bi * 64 + r0 + e) * N + bj * 64 + c0 + f;
            D[off] = fminf(D[off], acc[e][f]);
        }
}

// ---------------- double centering ----------------
__global__ void k_rowmean(const float* __restrict__ D, double* __restrict__ rm) {
    int i = blockIdx.x, t = threadIdx.x;
    const float* dr = D + (size_t)i * N;
    double s = 0;
    for (int j = t; j < N; j += 256) { double d = (double)dr[j]; s += d * d; }
    __shared__ double red[256];
    red[t] = s; __syncthreads();
    for (int off = 128; off; off >>= 1) { if (t < off) red[t] += red[t + off]; __syncthreads(); }
    if (t == 0) rm[i] = red[0] / (double)N;
}

__global__ void k_grand(const double* __restrict__ rm, double* __restrict__ gm) {
    int t = threadIdx.x;
    double s = 0;
    for (int i = t; i < N; i += 256) s += rm[i];
    __shared__ double red[256];
    red[t] = s; __syncthreads();
    for (int off = 128; off; off >>= 1) { if (t < off) red[t] += red[t + off]; __syncthreads(); }
    if (t == 0) gm[0] = red[0] / (double)N;
}

__global__ void k_buildB(const float* __restrict__ D, const double* __restrict__ rm,
                         const double* __restrict__ gm, double* __restrict__ A) {
    int idx = blockIdx.x * 256 + threadIdx.x;
    int i = idx >> 11, j = idx & 2047;
    double d = (double)D[idx];
    A[idx] = -0.5 * (d * d - rm[i] - rm[j] + gm[0]);
}

__global__ void k_setV(float* __restrict__ V) {
    int idx = blockIdx.x * 256 + threadIdx.x;
    int i = idx >> 11, j = idx & 2047;
    V[idx] = (i == j) ? 1.f : 0.f;
}

// ---------------- Jacobi control ----------------
__global__ void k_initflags(unsigned* flags) { flags[0] = 0u; flags[1] = 0u; flags[2] = 0u; }
// once per sweep: convergence check on previous sweep's accumulated maxima, then reset
__global__ void k_sweepctl(unsigned* flags) {
    if (!flags[2]) {
        float mo = __uint_as_float(flags[0]), md = __uint_as_float(flags[1]);
        if (md > 0.f && mo <= 2e-9f * md) { flags[2] = 1u; return; }
        flags[0] = 0u; flags[1] = 0u;
    }
}

// ---------------- local 32x32 Jacobi on a team pair (fp64 M,Q) ----------------
// Adaptive 1-2 cyclic passes. Writes rotated diagonal tile back to A.
// LDS stride 33 doubles: col/row access 2-way bank aliasing (free on CDNA4).
__global__ void __launch_bounds__(256) k_local(double* __restrict__ A, double* __restrict__ qb,
                                               int* __restrict__ qfl, unsigned* __restrict__ flags,
                                               int round) {
    int p = blockIdx.x, t = threadIdx.x;
    if (flags[2]) { if (t == 0) qfl[p] = 0; return; }
    __shared__ double M[32][33], Q[32][33];
    __shared__ double cA[16], sA[16];
    __shared__ int ppA[16], qqA[16];
    __shared__ float red1[256], red2[256];
    __shared__ int everr, anyr;
    int bi, bj; rr_pairN(round, p, NB, bi, bj);

    float offm = 0.f, diagm = 0.f;
    for (int e = 0; e < 4; e++) {
        int idx = t + e * 256; int x = idx >> 5, y = idx & 31;
        int gr = (x < 16) ? bi * 16 + x : bj * 16 + (x - 16);
        int gc = (y < 16) ? bi * 16 + y : bj * 16 + (y - 16);
        double v = A[(size_t)gr * N + gc];
        M[x][y] = v;
        float av = (float)fabs(v);
        if (x == y) diagm = fmaxf(diagm, av); else offm = fmaxf(offm, av);
        Q[x][y] = (x == y) ? 1.0 : 0.0;
    }
    red1[t] = offm; red2[t] = diagm;
    if (t == 0) { everr = 0; }
    __syncthreads();
    for (int off = 128; off; off >>= 1) {
        if (t < off) { red1[t] = fmaxf(red1[t], red1[t + off]); red2[t] = fmaxf(red2[t], red2[t + off]); }
        __syncthreads();
    }
    float dmaxf = red2[0], off0 = red1[0];
    if (t == 0) { atomicMax(flags + 0, __float_as_uint(off0)); atomicMax(flags + 1, __float_as_uint(dmaxf)); }
    double dmax = (double)dmaxf;
    if ((double)off0 <= 1e-9 * dmax) { if (t == 0) qfl[p] = 0; return; }
    double thr = fmax(1e-13 * dmax, 1e-5 * (double)off0);
    // far from converged -> 2 cyclic passes (better per-sweep contraction)
    int passes = (off0 > 3e-4f * dmaxf) ? 2 : 1;

    for (int ps = 0; ps < passes; ps++) {
        if (t == 0) anyr = 0;
        __syncthreads();
        for (int ir = 0; ir < 31; ir++) {
            if (t < 16) {
                int pp, qq; rr_pairN(ir, t, 32, pp, qq);
                double app = M[pp][pp], aqq = M[qq][qq], apq = M[pp][qq];
                double c = 1.0, sn = 0.0;
                if (fabs(apq) > thr) {
                    double tau = (aqq - app) / (2.0 * apq);
                    double tt2 = ((tau >= 0.0) ? 1.0 : -1.0) / (fabs(tau) + sqrt(1.0 + tau * tau));
                    c = 1.0 / sqrt(1.0 + tt2 * tt2);
                    sn = tt2 * c;
                    everr = 1; anyr = 1;
                }
                ppA[t] = pp; qqA[t] = qq; cA[t] = c; sA[t] = sn;
            }
            __syncthreads();
            // col updates: M <- M*J, Q <- Q*J  (512 slots, 2/thread)
            for (int e = 0; e < 2; e++) {
                int slot = t + e * 256; int mm = slot >> 5, k = slot & 31;
                double sn = sA[mm];
                if (sn != 0.0) {
                    int pp = ppA[mm], qq = qqA[mm]; double c = cA[mm];
                    double a = M[k][pp], b = M[k][qq];
                    M[k][pp] = c * a - sn * b; M[k][qq] = sn * a + c * b;
                    a = Q[k][pp]; b = Q[k][qq];
                    Q[k][pp] = c * a - sn * b; Q[k][qq] = sn * a + c * b;
                }
            }
            __syncthreads();
            // row updates: M <- J^T * M
            for (int e = 0; e < 2; e++) {
                int slot = t + e * 256; int mm = slot >> 5, k = slot & 31;
                double sn = sA[mm];
                if (sn != 0.0) {
                    int pp = ppA[mm], qq = qqA[mm]; double c = cA[mm];
                    double a = M[pp][k], b = M[qq][k];
                    M[pp][k] = c * a - sn * b; M[qq][k] = sn * a + c * b;
                }
            }
            __syncthreads();
        }
        int cont = anyr;
        __syncthreads();
        if (!cont) break;
    }
    int ev = everr;
    if (t == 0) qfl[p] = ev;
    if (ev) {
        for (int e = 0; e < 4; e++) {
            int idx = t + e * 256; int x = idx >> 5, y = idx & 31;
            qb[(size_t)p * 1024 + idx] = Q[x][y];
            int gr = (x < 16) ? bi * 16 + x : bj * 16 + (x - 16);
            int gc = (y < 16) ? bi * 16 + y : bj * 16 + (y - 16);
            A[(size_t)gr * N + gc] = M[x][y];
        }
    }
}

// fused apply, 1-D compact grid of NTRI + NVS blocks.
// task < NTRI: A <- Qr^T A Qc on upper-tri pair tile (pr<pc), writes tile+mirror.
// else: V <- V*Q (f32, 64-row stripe).
__global__ void __launch_bounds__(256) k_apply(double* __restrict__ A, float* __restrict__ V,
                                               const double* __restrict__ qb,
                                               const int* __restrict__ qfl,
                                               const unsigned* __restrict__ flags, int round) {
    if (flags[2]) return;
    int t = threadIdx.x;
    int task = blockIdx.x;
    if (task < NTRI) {
        // triangular decode: pr < pc over 64 teams
        int pr = 0, rem = task;
        while (rem >= 63 - pr) { rem -= 63 - pr; pr++; }
        int pc = pr + 1 + rem;
        int fr = qfl[pr], fc = qfl[pc];
        if (!fr && !fc) return;
        __shared__ double T[32][33], Qb[32][33];
        int bir, bjr, bic, bjc;
        rr_pairN(round, pr, NB, bir, bjr);
        rr_pairN(round, pc, NB, bic, bjc);
        for (int e = 0; e < 4; e++) {
            int idx = t + e * 256; int a = idx >> 5, b = idx & 31;
            if (fr) Qb[a][b] = qb[(size_t)pr * 1024 + idx];
            int gr = (a < 16) ? bir * 16 + a : bjr * 16 + (a - 16);
            int gc = (b < 16) ? bic * 16 + b : bjc * 16 + (b - 16);
            T[a][b] = A[(size_t)gr * N + gc];
        }
        __syncthreads();
        int x0 = (t >> 4) * 2, c0 = (t & 15) * 2;
        if (fr) {
            double acc[2][2] = {};
            for (int y = 0; y < 32; y++) {
                double q0 = Qb[y][x0], q1 = Qb[y][x0 + 1];
                double v0 = T[y][c0], v1 = T[y][c0 + 1];
                acc[0][0] += q0 * v0; acc[0][1] += q0 * v1;
                acc[1][0] += q1 * v0; acc[1][1] += q1 * v1;
            }
            __syncthreads();
            T[x0][c0] = acc[0][0]; T[x0][c0 + 1] = acc[0][1];
            T[x0 + 1][c0] = acc[1][0]; T[x0 + 1][c0 + 1] = acc[1][1];
            __syncthreads();
        }
        if (fc) {
            for (int e = 0; e < 4; e++) {
                int idx = t + e * 256; int a = idx >> 5, b = idx & 31;
                Qb[a][b] = qb[(size_t)pc * 1024 + idx];
            }
            __syncthreads();
            double acc[2][2] = {};
            for (int y = 0; y < 32; y++) {
                double v0 = T[x0][y], v1 = T[x0 + 1][y];
                double q0 = Qb[y][c0], q1 = Qb[y][c0 + 1];
                acc[0][0] += v0 * q0; acc[0][1] += v0 * q1;
                acc[1][0] += v1 * q0; acc[1][1] += v1 * q1;
            }
            __syncthreads();
            T[x0][c0] = acc[0][0]; T[x0][c0 + 1] = acc[0][1];
            T[x0 + 1][c0] = acc[1][0]; T[x0 + 1][c0 + 1] = acc[1][1];
            __syncthreads();
        }
        for (int e = 0; e < 4; e++) {
            int idx = t + e * 256; int a = idx >> 5, b = idx & 31;
            int gr = (a < 16) ? bir * 16 + a : bjr * 16 + (a - 16);
            int gc = (b < 16) ? bic * 16 + b : bjc * 16 + (b - 16);
            A[(size_t)gr * N + gc] = T[a][b];
            int gr2 = (a < 16) ? bic * 16 + a : bjc * 16 + (a - 16);
            int gc2 = (b < 16) ? bir * 16 + b : bjr * 16 + (b - 16);
            A[(size_t)gr2 * N + gc2] = T[b][a];
        }
    } else {
        int v = task - NTRI; int p = v >> 5, rt = v & 31;
        if (!qfl[p]) return;
        __shared__ float Qs[32][33], Tv[64][33];
        int bi, bj; rr_pairN(round, p, NB, bi, bj);
        for (int e = 0; e < 4; e++) {
            int idx = t + e * 256; int a = idx >> 5, b = idx & 31;
            Qs[a][b] = (float)qb[(size_t)p * 1024 + idx];
        }
        for (int e = 0; e < 8; e++) {
            int idx = t + e * 256; int a = idx >> 5, b = idx & 31;
            int gc = (b < 16) ? bi * 16 + b : bj * 16 + (b - 16);
            Tv[a][b] = V[(size_t)(rt * 64 + a) * N + gc];
        }
        __syncthreads();
        int r0 = (t >> 4) * 4, c0 = (t & 15) * 2;
        float acc[4][2] = {};
        for (int y = 0; y < 32; y++) {
            float q0 = Qs[y][c0], q1 = Qs[y][c0 + 1];
            for (int e = 0; e < 4; e++) {
                float vv = Tv[r0 + e][y];
                acc[e][0] += vv * q0; acc[e][1] += vv * q1;
            }
        }
        for (int e = 0; e < 4; e++)
            for (int f = 0; f < 2; f++) {
                int x = c0 + f;
                int gc = (x < 16) ? bi * 16 + x : bj * 16 + (x - 16);
                V[(size_t)(rt * 64 + r0 + e) * N + gc] = acc[e][f];
            }
    }
}

// ---------------- epilogue ----------------
__global__ void k_lambda(const double* __restrict__ A, double* __restrict__ lam) {
    int i = blockIdx.x * 256 + threadIdx.x;
    if (i < N) lam[i] = A[(size_t)i * N + i];
}

__global__ void __launch_bounds__(1024) k_sort(const double* __restrict__ lam,
                                               double* __restrict__ lams, int* __restrict__ order) {
    __shared__ double v[2048]; __shared__ int ix[2048];
    int t = threadIdx.x;
    v[t] = lam[t]; v[t + 1024] = lam[t + 1024];
    ix[t] = t; ix[t + 1024] = t + 1024;
    __syncthreads();
    for (int k = 2; k <= 2048; k <<= 1) {
        for (int j = k >> 1; j > 0; j >>= 1) {
            int l = ((t & ~(j - 1)) << 1) | (t & (j - 1));
            int partner = l | j;
            double va = v[l], vb = v[partner]; int ia = ix[l], ib = ix[partner];
            bool before = (va > vb) || (va == vb && ia < ib);
            bool asc = ((l & k) == 0);
            bool doSwap = asc ? (!before) : before;
            if (doSwap) { v[l] = vb; v[partner] = va; ix[l] = ib; ix[partner] = ia; }
            __syncthreads();
        }
    }
    lams[t] = v[t]; lams[t + 1024] = v[t + 1024];
    order[t] = ix[t]; order[t + 1024] = ix[t + 1024];
}

__global__ void k_out(const float* __restrict__ Vm, const double* __restrict__ lams,
                      const int* __restrict__ order, float* __restrict__ out) {
    int c = blockIdx.x, t = threadIdx.x;
    int col = order[c];
    __shared__ float rv[256]; __shared__ int ri[256];
    float bv = -1.f; int bidx = N;
    for (int i = t; i < N; i += 256) {
        float av = fabsf(Vm[(size_t)i * N + col]);
        if (av > bv || (av == bv && i < bidx)) { bv = av; bidx = i; }
    }
    rv[t] = bv; ri[t] = bidx;
    __syncthreads();
    for (int off = 128; off; off >>= 1) {
        if (t < off) {
            if (rv[t + off] > rv[t] || (rv[t + off] == rv[t] && ri[t + off] < ri[t])) {
                rv[t] = rv[t + off]; ri[t] = ri[t + off];
            }
        }
        __syncthreads();
    }
    float sv = Vm[(size_t)ri[0] * N + col];
    float s = (sv > 0.f) ? 1.f : ((sv < 0.f) ? -1.f : 0.f);
    double lv = lams[c];
    float f = s * (float)sqrt(lv > 0.0 ? lv : 0.0);
    for (int i = t; i < N; i += 256) out[(size_t)i * NC + c] = Vm[(size_t)i * N + col] * f;
}

extern "C" void kernel_launch(void* const* d_in, const int* in_sizes, int n_in,
                              void* d_out, int out_size, void* d_ws, size_t ws_size,
                              hipStream_t stream) {
    (void)in_sizes; (void)n_in; (void)out_size; (void)ws_size;
    const float* X = (const float*)d_in[0];
    float* out = (float*)d_out;

    double* rm  = (double*)d_ws;                 // N
    double* gm  = rm + N;                        // 1 (+7 pad)
    double* lam = gm + 8;                        // N
    double* lams= lam + N;                       // N
    double* A   = lams + N;                      // N*N fp64
    double* qb  = A + (size_t)N * N;             // NPAIRS*1024 fp64
    float* Dg   = (float*)(qb + (size_t)NPAIRS * 1024); // N*N f32
    float* Vm   = Dg + (size_t)N * N;            // N*N f32
    float* sq   = Vm + (size_t)N * N;            // N
    int* order  = (int*)(sq + N);                // N
    int* qfl    = order + N;                     // NPAIRS
    unsigned* flags = (unsigned*)(qfl + NPAIRS); // 3
    float* dist = (float*)A;                     // alias: dist dies before A is born

    // 1. pairwise distances
    k_rowsq<<<N / 4, 256, 0, stream>>>(X, sq);
    k_dist<<<dim3(32, 32), 256, 0, stream>>>(X, sq, dist);

    // 2. KNN graph
    k_knn<<<N, 256, 0, stream>>>(dist, Dg);
    k_symdiag<<<(N * N) / 256, 256, 0, stream>>>(Dg);

    // 3. blocked Floyd-Warshall
    for (int kb = 0; kb < N / 64; kb++) {
        k_fw12<<<63, 256, 0, stream>>>(Dg, kb);
        k_fw3<<<dim3(32, 32), 256, 0, stream>>>(Dg, kb);
    }

    // 4. double centering -> B (fp64)
    k_rowmean<<<N, 256, 0, stream>>>(Dg, rm);
    k_grand<<<1, 256, 0, stream>>>(rm, gm);
    k_buildB<<<(N * N) / 256, 256, 0, stream>>>(Dg, rm, gm, A);
    k_setV<<<(N * N) / 256, 256, 0, stream>>>(Vm);
    k_initflags<<<1, 1, 0, stream>>>(flags);

    // 5. two-sided block Jacobi (128 teams of 16, adaptive 1-2 inner passes)
    for (int sw = 0; sw < NSWEEPS; sw++) {
        k_sweepctl<<<1, 1, 0, stream>>>(flags);
        for (int r = 0; r < NB - 1; r++) {
            k_local<<<NPAIRS, 256, 0, stream>>>(A, qb, qfl, flags, r);
            k_apply<<<NTRI + NVS, 256, 0, stream>>>(A, Vm, qb, qfl, flags, r);
        }
    }

    // 6. sort eigenvalues, sign-fix, scale, write output
    k_lambda<<<N / 256, 256, 0, stream>>>(A, lam);
    k_sort<<<1, 1024, 0, stream>>>(lam, lams, order);
    k_out<<<NC, 256, 0, stream>>>(Vm, lams, order, out);
}

// Round 9
// 100849.628 us; speedup vs baseline: 1.2813x; 1.2813x over previous
//
#include <hip/hip_runtime.h>
#include <math.h>

#define N 2048
#define DIMS 784
#define BIGV 1.0e6f
#define NC 784

// two-sided block Jacobi config: 128 teams of width 16, 32x32 local tiles
#define NB 128
#define NPAIRS 64
#define NSWEEPS 18
#define NTRI 2016      // 64*63/2 upper-tri pair tiles
#define NVS  2048      // 64 pairs * 32 V row-stripes

// round-robin pairing over nteams: round r in [0,nteams-1), pair m in [0,nteams/2)
__device__ __forceinline__ void rr_pairN(int r, int m, int nteams, int& bi, int& bj) {
    int n1 = nteams - 1;
    if (m == 0) { bi = n1; bj = r % n1; }
    else { bi = (r + m) % n1; bj = (r - m + n1) % n1; }
}

// ---------------- distances ----------------
__global__ void k_rowsq(const float* __restrict__ X, float* __restrict__ sq) {
    int wave = threadIdx.x >> 6, lane = threadIdx.x & 63;
    int row = blockIdx.x * 4 + wave;
    const float* xr = X + (size_t)row * DIMS;
    float s = 0.f;
    for (int k = lane; k < DIMS; k += 64) { float v = xr[k]; s += v * v; }
    for (int off = 32; off; off >>= 1) s += __shfl_down(s, off);
    if (lane == 0) sq[row] = s;
}

__global__ void __launch_bounds__(256) k_dist(const float* __restrict__ X,
                                              const float* __restrict__ sq,
                                              float* __restrict__ out) {
    __shared__ float As[64][17], Bs[64][17];
    int ti = blockIdx.y, tj = blockIdx.x, t = threadIdx.x;
    int tx = t & 15, ty = t >> 4;
    float acc[4][4] = {};
    for (int k0 = 0; k0 < DIMS; k0 += 16) {
        for (int e = 0; e < 4; e++) {
            int idx = t + e * 256; int r = idx >> 4, c = idx & 15;
            As[r][c] = X[(size_t)(ti * 64 + r) * DIMS + k0 + c];
            Bs[r][c] = X[(size_t)(tj * 64 + r) * DIMS + k0 + c];
        }
        __syncthreads();
        for (int k = 0; k < 16; k++) {
            float a[4], b[4];
            for (int e = 0; e < 4; e++) a[e] = As[ty * 4 + e][k];
            for (int f = 0; f < 4; f++) b[f] = Bs[tx * 4 + f][k];
            for (int e = 0; e < 4; e++)
                for (int f = 0; f < 4; f++) acc[e][f] += a[e] * b[f];
        }
        __syncthreads();
    }
    for (int e = 0; e < 4; e++)
        for (int f = 0; f < 4; f++) {
            int gi = ti * 64 + ty * 4 + e, gj = tj * 64 + tx * 4 + f;
            float d2 = sq[gi] + sq[gj] - 2.f * acc[e][f];
            out[(size_t)gi * N + gj] = sqrtf(fmaxf(d2, 0.f));
        }
}

// ---------------- KNN graph ----------------
__global__ void k_knn(const float* __restrict__ dist, float* __restrict__ G) {
    int i = blockIdx.x, t = threadIdx.x;
    float bv[6]; int bidx[6];
    for (int k = 0; k < 6; k++) { bv[k] = 3.4e38f; bidx[k] = N; }
    const float* dr = dist + (size_t)i * N;
    for (int j = t; j < N; j += 256) {
        float v = dr[j];
        bool ins = (v < bv[5]) || (v == bv[5] && j < bidx[5]);
        if (ins) {
            int k = 5;
            while (k > 0) {
                bool mv = (v < bv[k - 1]) || (v == bv[k - 1] && j < bidx[k - 1]);
                if (!mv) break;
                bv[k] = bv[k - 1]; bidx[k] = bidx[k - 1]; k--;
            }
            bv[k] = v; bidx[k] = j;
        }
    }
    __shared__ float lv[256][6]; __shared__ int li[256][6];
    for (int k = 0; k < 6; k++) { lv[t][k] = bv[k]; li[t][k] = bidx[k]; }
    __syncthreads();
    for (int off = 128; off >= 1; off >>= 1) {
        if (t < off) {
            float av[6], cv[6]; int ai[6], ci[6];
            for (int k = 0; k < 6; k++) { av[k] = lv[t][k]; ai[k] = li[t][k]; cv[k] = lv[t + off][k]; ci[k] = li[t + off][k]; }
            float mv[6]; int mi[6]; int pa = 0, pb = 0;
            for (int k = 0; k < 6; k++) {
                bool ta;
                if (pa >= 6) ta = false;
                else if (pb >= 6) ta = true;
                else ta = (av[pa] < cv[pb]) || (av[pa] == cv[pb] && ai[pa] < ci[pb]);
                if (ta) { mv[k] = av[pa]; mi[k] = ai[pa]; pa++; }
                else    { mv[k] = cv[pb]; mi[k] = ci[pb]; pb++; }
            }
            for (int k = 0; k < 6; k++) { lv[t][k] = mv[k]; li[t][k] = mi[k]; }
        }
        __syncthreads();
    }
    float sv[6]; int si[6];
    for (int k = 0; k < 6; k++) { sv[k] = lv[0][k]; si[k] = li[0][k]; }
    for (int j = t; j < N; j += 256) {
        float val = BIGV;
        for (int k = 0; k < 6; k++) if (j == si[k]) val = sv[k];
        G[(size_t)i * N + j] = val;
    }
}

__global__ void k_symdiag(float* __restrict__ G) {
    int idx = blockIdx.x * 256 + threadIdx.x;
    int i = idx >> 11, j = idx & 2047;
    if (i == j) { G[idx] = 0.f; return; }
    if (j > i) {
        float a = G[(size_t)i * N + j], b = G[(size_t)j * N + i];
        float m = fminf(a, b);
        G[(size_t)i * N + j] = m; G[(size_t)j * N + i] = m;
    }
}

// ---------------- blocked Floyd-Warshall ----------------
__global__ void __launch_bounds__(256) k_fw12(float* __restrict__ D, int kb) {
    __shared__ float KK[64][65], C[64][65];
    int bx = blockIdx.x, t = threadIdx.x;
    for (int e = 0; e < 16; e++) { int idx = t + e * 256; int r = idx >> 6, c = idx & 63;
        KK[r][c] = D[(size_t)(kb * 64 + r) * N + kb * 64 + c]; }
    __syncthreads();
    int r0 = t >> 2, c0 = (t & 3) * 16;
    for (int k = 0; k < 64; k++) {
        float dk = KK[r0][k];
        for (int c = 0; c < 16; c++) KK[r0][c0 + c] = fminf(KK[r0][c0 + c], dk + KK[k][c0 + c]);
        __syncthreads();
    }
    if (bx == 62) {
        for (int e = 0; e < 16; e++) { int idx = t + e * 256; int r = idx >> 6, c = idx & 63;
            D[(size_t)(kb * 64 + r) * N + kb * 64 + c] = KK[r][c]; }
        return;
    }
    bool rowstripe = bx < 31;
    int o = rowstripe ? bx : bx - 31;
    o += (o >= kb) ? 1 : 0;
    int baseR = rowstripe ? kb : o;
    int baseC = rowstripe ? o : kb;
    for (int e = 0; e < 16; e++) { int idx = t + e * 256; int r = idx >> 6, c = idx & 63;
        C[r][c] = D[(size_t)(baseR * 64 + r) * N + baseC * 64 + c]; }
    __syncthreads();
    if (rowstripe) {
        for (int k = 0; k < 64; k++) {
            float dk = KK[r0][k];
            for (int c = 0; c < 16; c++) C[r0][c0 + c] = fminf(C[r0][c0 + c], dk + C[k][c0 + c]);
            __syncthreads();
        }
    } else {
        for (int k = 0; k < 64; k++) {
            float dk = C[r0][k];
            for (int c = 0; c < 16; c++) C[r0][c0 + c] = fminf(C[r0][c0 + c], dk + KK[k][c0 + c]);
            __syncthreads();
        }
    }
    for (int e = 0; e < 16; e++) { int idx = t + e * 256; int r = idx >> 6, c = idx & 63;
        D[(size_t)(baseR * 64 + r) * N + baseC * 64 + c] = C[r][c]; }
}

__global__ void __launch_bounds__(256) k_fw3(float* __restrict__ D, int kb) {
    int bi = blockIdx.y, bj = blockIdx.x;
    if (bi == kb || bj == kb) return;
    __shared__ float R[64][65], Cl[64][65];
    int t = threadIdx.x;
    for (int e = 0; e < 16; e++) { int idx = t + e * 256; int r = idx >> 6, c = idx & 63;
        R[r][c]  = D[(size_t)(bi * 64 + r) * N + kb * 64 + c];
        Cl[r][c] = D[(size_t)(kb * 64 + r) * N + bj * 64 + c]; }
    __syncthreads();
    int r0 = (t >> 4) * 4, c0 = (t & 15) * 4;
    float acc[4][4];
    for (int e = 0; e < 4; e++) for (int f = 0; f < 4; f++) acc[e][f] = 3.4e38f;
    for (int k = 0; k < 64; k++) {
        float a[4], b[4];
        for (int e = 0; e < 4; e++) a[e] = R[r0 + e][k];
        for (int f = 0; f < 4; f++) b[f] = Cl[k][c0 + f];
        for (int e = 0; e < 4; e++)
            for (int f = 0; f < 4; f++) acc[e][f] = fminf(acc[e][f], a[e] + b[f]);
    }
    for (int e = 0; e < 4; e++)
        for (int f = 0; f < 4; f++) {
            size_t off = (size_t)(bi * 64 + r0 + e) * N + bj * 64 + c0 + f;
            D[off] = fminf(D[off], acc[e][f]);
        }
}

// ---------------- double centering ----------------
__global__ void k_rowmean(const float* __restrict__ D, double* __restrict__ rm) {
    int i = blockIdx.x, t = threadIdx.x;
    const float* dr = D + (size_t)i * N;
    double s = 0;
    for (int j = t; j < N; j += 256) { double d = (double)dr[j]; s += d * d; }
    __shared__ double red[256];
    red[t] = s; __syncthreads();
    for (int off = 128; off; off >>= 1) { if (t < off) red[t] += red[t + off]; __syncthreads(); }
    if (t == 0) rm[i] = red[0] / (double)N;
}

__global__ void k_grand(const double* __restrict__ rm, double* __restrict__ gm) {
    int t = threadIdx.x;
    double s = 0;
    for (int i = t; i < N; i += 256) s += rm[i];
    __shared__ double red[256];
    red[t] = s; __syncthreads();
    for (int off = 128; off; off >>= 1) { if (t < off) red[t] += red[t + off]; __syncthreads(); }
    if (t == 0) gm[0] = red[0] / (double)N;
}

__global__ void k_buildB(const float* __restrict__ D, const double* __restrict__ rm,
                         const double* __restrict__ gm, double* __restrict__ A) {
    int idx = blockIdx.x * 256 + threadIdx.x;
    int i = idx >> 11, j = idx & 2047;
    double d = (double)D[idx];
    A[idx] = -0.5 * (d * d - rm[i] - rm[j] + gm[0]);
}

__global__ void k_setV(float* __restrict__ V) {
    int idx = blockIdx.x * 256 + threadIdx.x;
    int i = idx >> 11, j = idx & 2047;
    V[idx] = (i == j) ? 1.f : 0.f;
}

// ---------------- Jacobi control ----------------
__global__ void k_initflags(unsigned* flags) { flags[0] = 0u; flags[1] = 0u; flags[2] = 0u; }
// once per sweep: convergence check on previous sweep's accumulated maxima, then reset
__global__ void k_sweepctl(unsigned* flags) {
    if (!flags[2]) {
        float mo = __uint_as_float(flags[0]), md = __uint_as_float(flags[1]);
        if (md > 0.f && mo <= 2e-9f * md) { flags[2] = 1u; return; }
        flags[0] = 0u; flags[1] = 0u;
    }
}

// ---------------- local 32x32 Jacobi on a team pair (fp64 M,Q) ----------------
// Single cyclic pass (31 micro-rounds x 16 rotations). Writes rotated diagonal
// tile back to A. LDS stride 33 doubles: col/row access 2-way aliasing (free).
__global__ void __launch_bounds__(256) k_local(double* __restrict__ A, double* __restrict__ qb,
                                               int* __restrict__ qfl, unsigned* __restrict__ flags,
                                               int round) {
    int p = blockIdx.x, t = threadIdx.x;
    if (flags[2]) { if (t == 0) qfl[p] = 0; return; }
    __shared__ double M[32][33], Q[32][33];
    __shared__ double cA[16], sA[16];
    __shared__ int ppA[16], qqA[16];
    __shared__ float red1[256], red2[256];
    __shared__ int everr;
    int bi, bj; rr_pairN(round, p, NB, bi, bj);

    float offm = 0.f, diagm = 0.f;
    for (int e = 0; e < 4; e++) {
        int idx = t + e * 256; int x = idx >> 5, y = idx & 31;
        int gr = (x < 16) ? bi * 16 + x : bj * 16 + (x - 16);
        int gc = (y < 16) ? bi * 16 + y : bj * 16 + (y - 16);
        double v = A[(size_t)gr * N + gc];
        M[x][y] = v;
        float av = (float)fabs(v);
        if (x == y) diagm = fmaxf(diagm, av); else offm = fmaxf(offm, av);
        Q[x][y] = (x == y) ? 1.0 : 0.0;
    }
    red1[t] = offm; red2[t] = diagm;
    if (t == 0) everr = 0;
    __syncthreads();
    for (int off = 128; off; off >>= 1) {
        if (t < off) { red1[t] = fmaxf(red1[t], red1[t + off]); red2[t] = fmaxf(red2[t], red2[t + off]); }
        __syncthreads();
    }
    float dmaxf = red2[0], off0 = red1[0];
    if (t == 0) { atomicMax(flags + 0, __float_as_uint(off0)); atomicMax(flags + 1, __float_as_uint(dmaxf)); }
    double dmax = (double)dmaxf;
    if ((double)off0 <= 1e-9 * dmax) { if (t == 0) qfl[p] = 0; return; }
    double thr = fmax(1e-13 * dmax, 1e-5 * (double)off0);

    for (int ir = 0; ir < 31; ir++) {
        if (t < 16) {
            int pp, qq; rr_pairN(ir, t, 32, pp, qq);
            double app = M[pp][pp], aqq = M[qq][qq], apq = M[pp][qq];
            double c = 1.0, sn = 0.0;
            if (fabs(apq) > thr) {
                double tau = (aqq - app) / (2.0 * apq);
                double tt2 = ((tau >= 0.0) ? 1.0 : -1.0) / (fabs(tau) + sqrt(1.0 + tau * tau));
                c = 1.0 / sqrt(1.0 + tt2 * tt2);
                sn = tt2 * c;
                everr = 1;
            }
            ppA[t] = pp; qqA[t] = qq; cA[t] = c; sA[t] = sn;
        }
        __syncthreads();
        // col updates: M <- M*J, Q <- Q*J  (512 slots, 2/thread)
        for (int e = 0; e < 2; e++) {
            int slot = t + e * 256; int mm = slot >> 5, k = slot & 31;
            double sn = sA[mm];
            if (sn != 0.0) {
                int pp = ppA[mm], qq = qqA[mm]; double c = cA[mm];
                double a = M[k][pp], b = M[k][qq];
                M[k][pp] = c * a - sn * b; M[k][qq] = sn * a + c * b;
                a = Q[k][pp]; b = Q[k][qq];
                Q[k][pp] = c * a - sn * b; Q[k][qq] = sn * a + c * b;
            }
        }
        __syncthreads();
        // row updates: M <- J^T * M
        for (int e = 0; e < 2; e++) {
            int slot = t + e * 256; int mm = slot >> 5, k = slot & 31;
            double sn = sA[mm];
            if (sn != 0.0) {
                int pp = ppA[mm], qq = qqA[mm]; double c = cA[mm];
                double a = M[pp][k], b = M[qq][k];
                M[pp][k] = c * a - sn * b; M[qq][k] = sn * a + c * b;
            }
        }
        __syncthreads();
    }
    int ev = everr;
    if (t == 0) qfl[p] = ev;
    if (ev) {
        for (int e = 0; e < 4; e++) {
            int idx = t + e * 256; int x = idx >> 5, y = idx & 31;
            qb[(size_t)p * 1024 + idx] = Q[x][y];
            int gr = (x < 16) ? bi * 16 + x : bj * 16 + (x - 16);
            int gc = (y < 16) ? bi * 16 + y : bj * 16 + (y - 16);
            A[(size_t)gr * N + gc] = M[x][y];
        }
    }
}

// fused apply, 1-D compact grid of NTRI + NVS blocks.
// task < NTRI: A <- Qr^T A Qc on upper-tri pair tile (pr<pc), writes tile+mirror.
// else: V <- V*Q (f32, 64-row stripe).
__global__ void __launch_bounds__(256) k_apply(double* __restrict__ A, float* __restrict__ V,
                                               const double* __restrict__ qb,
                                               const int* __restrict__ qfl,
                                               const unsigned* __restrict__ flags, int round) {
    if (flags[2]) return;
    int t = threadIdx.x;
    int task = blockIdx.x;
    if (task < NTRI) {
        // triangular decode: pr < pc over 64 teams
        int pr = 0, rem = task;
        while (rem >= 63 - pr) { rem -= 63 - pr; pr++; }
        int pc = pr + 1 + rem;
        int fr = qfl[pr], fc = qfl[pc];
        if (!fr && !fc) return;
        __shared__ double T[32][33], Qb[32][33];
        int bir, bjr, bic, bjc;
        rr_pairN(round, pr, NB, bir, bjr);
        rr_pairN(round, pc, NB, bic, bjc);
        for (int e = 0; e < 4; e++) {
            int idx = t + e * 256; int a = idx >> 5, b = idx & 31;
            if (fr) Qb[a][b] = qb[(size_t)pr * 1024 + idx];
            int gr = (a < 16) ? bir * 16 + a : bjr * 16 + (a - 16);
            int gc = (b < 16) ? bic * 16 + b : bjc * 16 + (b - 16);
            T[a][b] = A[(size_t)gr * N + gc];
        }
        __syncthreads();
        int x0 = (t >> 4) * 2, c0 = (t & 15) * 2;
        if (fr) {
            double acc[2][2] = {};
            for (int y = 0; y < 32; y++) {
                double q0 = Qb[y][x0], q1 = Qb[y][x0 + 1];
                double v0 = T[y][c0], v1 = T[y][c0 + 1];
                acc[0][0] += q0 * v0; acc[0][1] += q0 * v1;
                acc[1][0] += q1 * v0; acc[1][1] += q1 * v1;
            }
            __syncthreads();
            T[x0][c0] = acc[0][0]; T[x0][c0 + 1] = acc[0][1];
            T[x0 + 1][c0] = acc[1][0]; T[x0 + 1][c0 + 1] = acc[1][1];
            __syncthreads();
        }
        if (fc) {
            for (int e = 0; e < 4; e++) {
                int idx = t + e * 256; int a = idx >> 5, b = idx & 31;
                Qb[a][b] = qb[(size_t)pc * 1024 + idx];
            }
            __syncthreads();
            double acc[2][2] = {};
            for (int y = 0; y < 32; y++) {
                double v0 = T[x0][y], v1 = T[x0 + 1][y];
                double q0 = Qb[y][c0], q1 = Qb[y][c0 + 1];
                acc[0][0] += v0 * q0; acc[0][1] += v0 * q1;
                acc[1][0] += v1 * q0; acc[1][1] += v1 * q1;
            }
            __syncthreads();
            T[x0][c0] = acc[0][0]; T[x0][c0 + 1] = acc[0][1];
            T[x0 + 1][c0] = acc[1][0]; T[x0 + 1][c0 + 1] = acc[1][1];
            __syncthreads();
        }
        for (int e = 0; e < 4; e++) {
            int idx = t + e * 256; int a = idx >> 5, b = idx & 31;
            int gr = (a < 16) ? bir * 16 + a : bjr * 16 + (a - 16);
            int gc = (b < 16) ? bic * 16 + b : bjc * 16 + (b - 16);
            A[(size_t)gr * N + gc] = T[a][b];
            int gr2 = (a < 16) ? bic * 16 + a : bjc * 16 + (a - 16);
            int gc2 = (b < 16) ? bir * 16 + b : bjr * 16 + (b - 16);
            A[(size_t)gr2 * N + gc2] = T[b][a];
        }
    } else {
        int v = task - NTRI; int p = v >> 5, rt = v & 31;
        if (!qfl[p]) return;
        __shared__ float Qs[32][33], Tv[64][33];
        int bi, bj; rr_pairN(round, p, NB, bi, bj);
        for (int e = 0; e < 4; e++) {
            int idx = t + e * 256; int a = idx >> 5, b = idx & 31;
            Qs[a][b] = (float)qb[(size_t)p * 1024 + idx];
        }
        for (int e = 0; e < 8; e++) {
            int idx = t + e * 256; int a = idx >> 5, b = idx & 31;
            int gc = (b < 16) ? bi * 16 + b : bj * 16 + (b - 16);
            Tv[a][b] = V[(size_t)(rt * 64 + a) * N + gc];
        }
        __syncthreads();
        int r0 = (t >> 4) * 4, c0 = (t & 15) * 2;
        float acc[4][2] = {};
        for (int y = 0; y < 32; y++) {
            float q0 = Qs[y][c0], q1 = Qs[y][c0 + 1];
            for (int e = 0; e < 4; e++) {
                float vv = Tv[r0 + e][y];
                acc[e][0] += vv * q0; acc[e][1] += vv * q1;
            }
        }
        for (int e = 0; e < 4; e++)
            for (int f = 0; f < 2; f++) {
                int x = c0 + f;
                int gc = (x < 16) ? bi * 16 + x : bj * 16 + (x - 16);
                V[(size_t)(rt * 64 + r0 + e) * N + gc] = acc[e][f];
            }
    }
}

// ---------------- epilogue ----------------
__global__ void k_lambda(const double* __restrict__ A, double* __restrict__ lam) {
    int i = blockIdx.x * 256 + threadIdx.x;
    if (i < N) lam[i] = A[(size_t)i * N + i];
}

__global__ void __launch_bounds__(1024) k_sort(const double* __restrict__ lam,
                                               double* __restrict__ lams, int* __restrict__ order) {
    __shared__ double v[2048]; __shared__ int ix[2048];
    int t = threadIdx.x;
    v[t] = lam[t]; v[t + 1024] = lam[t + 1024];
    ix[t] = t; ix[t + 1024] = t + 1024;
    __syncthreads();
    for (int k = 2; k <= 2048; k <<= 1) {
        for (int j = k >> 1; j > 0; j >>= 1) {
            int l = ((t & ~(j - 1)) << 1) | (t & (j - 1));
            int partner = l | j;
            double va = v[l], vb = v[partner]; int ia = ix[l], ib = ix[partner];
            bool before = (va > vb) || (va == vb && ia < ib);
            bool asc = ((l & k) == 0);
            bool doSwap = asc ? (!before) : before;
            if (doSwap) { v[l] = vb; v[partner] = va; ix[l] = ib; ix[partner] = ia; }
            __syncthreads();
        }
    }
    lams[t] = v[t]; lams[t + 1024] = v[t + 1024];
    order[t] = ix[t]; order[t + 1024] = ix[t + 1024];
}

__global__ void k_out(const float* __restrict__ Vm, const double* __restrict__ lams,
                      const int* __restrict__ order, float* __restrict__ out) {
    int c = blockIdx.x, t = threadIdx.x;
    int col = order[c];
    __shared__ float rv[256]; __shared__ int ri[256];
    float bv = -1.f; int bidx = N;
    for (int i = t; i < N; i += 256) {
        float av = fabsf(Vm[(size_t)i * N + col]);
        if (av > bv || (av == bv && i < bidx)) { bv = av; bidx = i; }
    }
    rv[t] = bv; ri[t] = bidx;
    __syncthreads();
    for (int off = 128; off; off >>= 1) {
        if (t < off) {
            if (rv[t + off] > rv[t] || (rv[t + off] == rv[t] && ri[t + off] < ri[t])) {
                rv[t] = rv[t + off]; ri[t] = ri[t + off];
            }
        }
        __syncthreads();
    }
    float sv = Vm[(size_t)ri[0] * N + col];
    float s = (sv > 0.f) ? 1.f : ((sv < 0.f) ? -1.f : 0.f);
    double lv = lams[c];
    float f = s * (float)sqrt(lv > 0.0 ? lv : 0.0);
    for (int i = t; i < N; i += 256) out[(size_t)i * NC + c] = Vm[(size_t)i * N + col] * f;
}

extern "C" void kernel_launch(void* const* d_in, const int* in_sizes, int n_in,
                              void* d_out, int out_size, void* d_ws, size_t ws_size,
                              hipStream_t stream) {
    (void)in_sizes; (void)n_in; (void)out_size; (void)ws_size;
    const float* X = (const float*)d_in[0];
    float* out = (float*)d_out;

    double* rm  = (double*)d_ws;                 // N
    double* gm  = rm + N;                        // 1 (+7 pad)
    double* lam = gm + 8;                        // N
    double* lams= lam + N;                       // N
    double* A   = lams + N;                      // N*N fp64
    double* qb  = A + (size_t)N * N;             // NPAIRS*1024 fp64
    float* Dg   = (float*)(qb + (size_t)NPAIRS * 1024); // N*N f32
    float* Vm   = Dg + (size_t)N * N;            // N*N f32
    float* sq   = Vm + (size_t)N * N;            // N
    int* order  = (int*)(sq + N);                // N
    int* qfl    = order + N;                     // NPAIRS
    unsigned* flags = (unsigned*)(qfl + NPAIRS); // 3
    float* dist = (float*)A;                     // alias: dist dies before A is born

    // 1. pairwise distances
    k_rowsq<<<N / 4, 256, 0, stream>>>(X, sq);
    k_dist<<<dim3(32, 32), 256, 0, stream>>>(X, sq, dist);

    // 2. KNN graph
    k_knn<<<N, 256, 0, stream>>>(dist, Dg);
    k_symdiag<<<(N * N) / 256, 256, 0, stream>>>(Dg);

    // 3. blocked Floyd-Warshall
    for (int kb = 0; kb < N / 64; kb++) {
        k_fw12<<<63, 256, 0, stream>>>(Dg, kb);
        k_fw3<<<dim3(32, 32), 256, 0, stream>>>(Dg, kb);
    }

    // 4. double centering -> B (fp64)
    k_rowmean<<<N, 256, 0, stream>>>(Dg, rm);
    k_grand<<<1, 256, 0, stream>>>(rm, gm);
    k_buildB<<<(N * N) / 256, 256, 0, stream>>>(Dg, rm, gm, A);
    k_setV<<<(N * N) / 256, 256, 0, stream>>>(Vm);
    k_initflags<<<1, 1, 0, stream>>>(flags);

    // 5. two-sided block Jacobi (128 teams of 16, single inner pass)
    for (int sw = 0; sw < NSWEEPS; sw++) {
        k_sweepctl<<<1, 1, 0, stream>>>(flags);
        for (int r = 0; r < NB - 1; r++) {
            k_local<<<NPAIRS, 256, 0, stream>>>(A, qb, qfl, flags, r);
            k_apply<<<NTRI + NVS, 256, 0, stream>>>(A, Vm, qb, qfl, flags, r);
        }
    }

    // 6. sort eigenvalues, sign-fix, scale, write output
    k_lambda<<<N / 256, 256, 0, stream>>>(A, lam);
    k_sort<<<1, 1024, 0, stream>>>(lam, lams, order);
    k_out<<<NC, 256, 0, stream>>>(Vm, lams, order, out);
}